// Round 3
// baseline (270.628 us; speedup 1.0000x reference)
//
#include <hip/hip_runtime.h>
#include <stdint.h>

typedef unsigned int u32;
typedef unsigned short u16;
typedef unsigned long long u64;

#define NB 256                      // histogram bins over error in [0,1]
#define NC 20                       // classes
#define K1_BLOCK 256
#define NCTR (NC * NB)              // 5120 packed counters (tot lo16 | fg hi16)
#define DUMP_BYTES (NCTR * 4)       // u32 dump per block = 20480 B
#define FINAL_U32 (NCTR * 2)        // unpacked: tot[5120] then fg[5120]
#define OFF_CE   (FINAL_U32 * 4)    // = 40960
#define OFF_CNT  (OFF_CE + 4)
#define OFF_DUMPS 65536
#define RESERVED  OFF_DUMPS
#define NBLK_K1  2048

__device__ __forceinline__ float max4(float4 v) {
    return fmaxf(fmaxf(v.x, v.y), fmaxf(v.z, v.w));
}

// softmax + CE + packed histogram update for one point, fully register-resident
__device__ __forceinline__ void process_point(
    float4 v0, float4 v1, float4 v2, float4 v3, float4 v4, int t,
    u32* lds, float& ce_part, u32& cnt_part)
{
    float x[NC] = { v0.x, v0.y, v0.z, v0.w,  v1.x, v1.y, v1.z, v1.w,
                    v2.x, v2.y, v2.z, v2.w,  v3.x, v3.y, v3.z, v3.w,
                    v4.x, v4.y, v4.z, v4.w };
    float mx = fmaxf(fmaxf(fmaxf(max4(v0), max4(v1)), fmaxf(max4(v2), max4(v3))), max4(v4));

    float s = 0.f;
    #pragma unroll
    for (int c = 0; c < NC; ++c) { x[c] = __expf(x[c] - mx); s += x[c]; }
    float inv = 1.0f / s;

    float pt = 1.0f;                 // target prob (stays 1 -> log 0 if t==0 unused)
    #pragma unroll
    for (int c = 0; c < NC; ++c) {
        float p = x[c] * inv;
        bool is_t = (c == t);
        float err = is_t ? (1.0f - p) : p;
        pt = is_t ? p : pt;
        int b = (int)(err * (float)NB);
        b = b > NB - 1 ? NB - 1 : b;
        atomicAdd(&lds[c * NB + b], is_t ? 0x10001u : 1u);
    }
    if (t != 0) { ce_part -= __logf(pt); cnt_part++; }
}

// ---------------- kernel 1: softmax + CE + packed privatized histograms ----------------
__global__ __launch_bounds__(K1_BLOCK) void k1_hist(
    const float* __restrict__ logits, const int* __restrict__ tgt, int P,
    u32* __restrict__ dumps, float* __restrict__ ce_sum, u32* __restrict__ valid_cnt)
{
    __shared__ u32 lds[NCTR];            // 20 KiB

    for (int i = threadIdx.x; i < NCTR; i += K1_BLOCK) lds[i] = 0;
    __syncthreads();

    float ce_part = 0.f;
    u32   cnt_part = 0;

    const long long stride = (long long)NBLK_K1 * K1_BLOCK;
    long long idx = (long long)blockIdx.x * K1_BLOCK + threadIdx.x;

    // 2-point ILP main loop: issue both rows' loads before processing either
    for (; idx + stride < P; idx += 2 * stride) {
        const float* rowA = logits + idx * NC;
        const float* rowB = logits + (idx + stride) * NC;
        float4 a0 = *(const float4*)(rowA + 0);
        float4 a1 = *(const float4*)(rowA + 4);
        float4 a2 = *(const float4*)(rowA + 8);
        float4 a3 = *(const float4*)(rowA + 12);
        float4 a4 = *(const float4*)(rowA + 16);
        float4 b0 = *(const float4*)(rowB + 0);
        float4 b1 = *(const float4*)(rowB + 4);
        float4 b2 = *(const float4*)(rowB + 8);
        float4 b3 = *(const float4*)(rowB + 12);
        float4 b4 = *(const float4*)(rowB + 16);
        int tA = tgt[idx];
        int tB = tgt[idx + stride];
        process_point(a0, a1, a2, a3, a4, tA, lds, ce_part, cnt_part);
        process_point(b0, b1, b2, b3, b4, tB, lds, ce_part, cnt_part);
    }
    // tail
    for (; idx < P; idx += stride) {
        const float* row = logits + idx * NC;
        float4 a0 = *(const float4*)(row + 0);
        float4 a1 = *(const float4*)(row + 4);
        float4 a2 = *(const float4*)(row + 8);
        float4 a3 = *(const float4*)(row + 12);
        float4 a4 = *(const float4*)(row + 16);
        int t = tgt[idx];
        process_point(a0, a1, a2, a3, a4, t, lds, ce_part, cnt_part);
    }

    // per-wave reduction, direct global atomic
    #pragma unroll
    for (int off = 32; off > 0; off >>= 1) {
        ce_part  += __shfl_down(ce_part, off);
        cnt_part += __shfl_down(cnt_part, off);
    }
    if ((threadIdx.x & 63) == 0) {
        atomicAdd(ce_sum, ce_part);
        atomicAdd(valid_cnt, cnt_part);
    }
    __syncthreads();

    // non-atomic per-block dump (u16 halves safe: <=977 points per block)
    u32* d = dumps + (size_t)blockIdx.x * NCTR;
    for (int i = threadIdx.x; i < NCTR; i += K1_BLOCK) d[i] = lds[i];
}

// ---------------- kernel 2a: reduce + unpack per-block dumps ----------------
__global__ __launch_bounds__(256) void k2a_reduce(
    const u32* __restrict__ dumps, u32* __restrict__ final_hist, int nblk, int chunk)
{
    int counter = (blockIdx.x % 20) * 256 + threadIdx.x;   // 20*256 == 5120
    int part    = blockIdx.x / 20;
    int b0 = part * chunk;
    int b1 = b0 + chunk; if (b1 > nblk) b1 = nblk;
    u32 lo = 0, hi = 0;
    for (int blk = b0; blk < b1; ++blk) {
        u32 v = dumps[(size_t)blk * NCTR + counter];
        lo += v & 0xFFFFu;
        hi += v >> 16;
    }
    if (lo) atomicAdd(&final_hist[counter], lo);           // tot
    if (hi) atomicAdd(&final_hist[NCTR + counter], hi);    // fg
}

// ---------------- kernel 2b: per-class descending bin scan + finalize ----------------
__device__ __forceinline__ float jac_of(float gts, u32 cf, u32 ct)
{
    float I = gts - (float)cf;
    float U = gts + (float)ct - (float)cf;
    return 1.0f - I / U;
}

__global__ __launch_bounds__(256) void k2b_final(
    const u32* __restrict__ final_hist, const float* __restrict__ ce_sum,
    const u32* __restrict__ valid_cnt, float* __restrict__ outp)
{
    __shared__ u64 sc[NB];
    __shared__ float red[NB];
    int t = threadIdx.x;

    float lovsum = 0.f;
    int prescnt = 0;

    for (int c = 0; c < NC; ++c) {
        int b = NB - 1 - t;                 // descending error order
        u32 tot = final_hist[c * NB + b];
        u32 fg  = final_hist[NCTR + c * NB + b];
        u64 v = ((u64)fg << 32) | (u64)tot;

        sc[t] = v;
        __syncthreads();
        for (int off = 1; off < NB; off <<= 1) {
            u64 add = (t >= off) ? sc[t - off] : 0ull;
            __syncthreads();
            sc[t] += add;
            __syncthreads();
        }
        u64 incl  = sc[t];
        u64 total = sc[NB - 1];
        float gts = (float)(u32)(total >> 32);

        float contrib = 0.f;
        if (gts > 0.f) {
            u64 excl = incl - v;
            float jE = jac_of(gts, (u32)(excl >> 32), (u32)excl);
            float jI = jac_of(gts, (u32)(incl >> 32), (u32)incl);
            float eb = ((float)b + 0.5f) * (1.0f / (float)NB);
            contrib = eb * (jI - jE);
        }

        red[t] = contrib;
        __syncthreads();
        #pragma unroll
        for (int off = NB / 2; off > 0; off >>= 1) {
            if (t < off) red[t] += red[t + off];
            __syncthreads();
        }
        if (t == 0 && gts > 0.f) { lovsum += red[0]; prescnt++; }
        __syncthreads();
    }

    if (t == 0) {
        u32 vc = *valid_cnt; if (vc < 1u) vc = 1u;
        float ce = *ce_sum / (float)vc;
        int pc = prescnt < 1 ? 1 : prescnt;
        float lov = lovsum / (float)pc;
        outp[0] = 2.0f * ce;
        outp[1] = 6.0f * lov;
    }
}

// ---------------- launch ----------------
extern "C" void kernel_launch(void* const* d_in, const int* in_sizes, int n_in,
                              void* d_out, int out_size, void* d_ws, size_t ws_size,
                              hipStream_t stream)
{
    const float* logits = (const float*)d_in[0];
    const int*   tgt    = (const int*)d_in[1];
    int P = in_sizes[1];

    char* ws = (char*)d_ws;
    u32*  final_hist = (u32*)ws;
    float* ce_sum    = (float*)(ws + OFF_CE);
    u32*  valid_cnt  = (u32*)(ws + OFF_CNT);
    u32*  dumps      = (u32*)(ws + OFF_DUMPS);

    int nblk = NBLK_K1;
    size_t avail = ws_size > (size_t)RESERVED ? ws_size - RESERVED : 0;
    int maxblk = (int)(avail / DUMP_BYTES);
    if (maxblk < 1) maxblk = 1;
    if (nblk > maxblk) nblk = maxblk;

    hipMemsetAsync(d_ws, 0, RESERVED, stream);
    hipLaunchKernelGGL(k1_hist, dim3(nblk), dim3(K1_BLOCK), 0, stream,
                       logits, tgt, P, dumps, ce_sum, valid_cnt);
    int split = nblk >= 32 ? 32 : 1;
    int chunk = (nblk + split - 1) / split;
    hipLaunchKernelGGL(k2a_reduce, dim3(20 * split), dim3(256), 0, stream,
                       dumps, final_hist, nblk, chunk);
    hipLaunchKernelGGL(k2b_final, dim3(1), dim3(NB), 0, stream,
                       final_hist, ce_sum, valid_cnt, (float*)d_out);
}

// Round 4
// 193.565 us; speedup vs baseline: 1.3981x; 1.3981x over previous
//
#include <hip/hip_runtime.h>
#include <stdint.h>

typedef unsigned int u32;
typedef unsigned char u8;
typedef unsigned long long u64;

#define NB 256                      // histogram bins over error in [0,1]
#define NC 20                       // classes
#define BLK 256
#define NCTR (NC * NB)              // 5120 packed counters (tot lo16 | fg hi16)
#define DUMP_BYTES (NCTR * 4)       // 20480 B per block
#define FINAL_U32 (NCTR * 2)        // unpacked final hist: tot[5120] then fg[5120]
#define OFF_CE   (FINAL_U32 * 4)    // 40960
#define OFF_CNT  (OFF_CE + 4)
#define OFF_DUMPS 65536
#define RESERVED  OFF_DUMPS
#define NBLK 1024

// ---------------- float4 helpers ----------------
__device__ __forceinline__ float4 f4max(float4 a, float4 b) {
    return make_float4(fmaxf(a.x,b.x), fmaxf(a.y,b.y), fmaxf(a.z,b.z), fmaxf(a.w,b.w));
}
__device__ __forceinline__ float4 f4add(float4 a, float4 b) {
    return make_float4(a.x+b.x, a.y+b.y, a.z+b.z, a.w+b.w);
}
__device__ __forceinline__ float4 f4expsub(float4 a, float m) {
    return make_float4(__expf(a.x-m), __expf(a.y-m), __expf(a.z-m), __expf(a.w-m));
}
__device__ __forceinline__ u32 bin1(float e, float inv, int c, int t, float& pt) {
    float p = e * inv;
    if (c == t) pt = p;
    float err = (c == t) ? 1.0f - p : p;
    int b = (int)(err * 256.0f);
    return (u32)(b > 255 ? 255 : b);
}
__device__ __forceinline__ u32 pack4(float4 e, float inv, int cb, int t, float& pt) {
    return  bin1(e.x, inv, cb+0, t, pt)
         | (bin1(e.y, inv, cb+1, t, pt) << 8)
         | (bin1(e.z, inv, cb+2, t, pt) << 16)
         | (bin1(e.w, inv, cb+3, t, pt) << 24);
}

// ---------------- k1a: streaming softmax + CE + bin-pack (no LDS) ----------------
__global__ void k1a_bins(
    const float* __restrict__ logits, const int* __restrict__ tgt, int P,
    u32* __restrict__ bins, u8* __restrict__ t8,
    float* __restrict__ ce_sum, u32* __restrict__ valid_cnt)
{
    int tid = blockIdx.x * BLK + threadIdx.x;
    float ce_part = 0.f;
    u32   cnt_part = 0;

    for (int idx = tid; idx < P; idx += NBLK * BLK) {
        const float4* row = (const float4*)(logits + (size_t)idx * NC);
        float4 v0 = row[0], v1 = row[1], v2 = row[2], v3 = row[3], v4 = row[4];
        int t = tgt[idx];

        float4 m4 = f4max(f4max(v0, v1), f4max(v2, v3));
        m4 = f4max(m4, v4);
        float mx = fmaxf(fmaxf(m4.x, m4.y), fmaxf(m4.z, m4.w));

        float4 e0 = f4expsub(v0, mx);
        float4 e1 = f4expsub(v1, mx);
        float4 e2 = f4expsub(v2, mx);
        float4 e3 = f4expsub(v3, mx);
        float4 e4 = f4expsub(v4, mx);

        float4 s4 = f4add(f4add(e0, e1), f4add(e2, e3));
        s4 = f4add(s4, e4);
        float s = (s4.x + s4.y) + (s4.z + s4.w);
        float inv = 1.0f / s;

        float pt = 1.0f;
        u32 w0 = pack4(e0, inv, 0,  t, pt);
        u32 w1 = pack4(e1, inv, 4,  t, pt);
        u32 w2 = pack4(e2, inv, 8,  t, pt);
        u32 w3 = pack4(e3, inv, 12, t, pt);
        u32 w4 = pack4(e4, inv, 16, t, pt);

        bins[idx]         = w0;
        bins[P + idx]     = w1;
        bins[2 * P + idx] = w2;
        bins[3 * P + idx] = w3;
        bins[4 * P + idx] = w4;
        t8[idx] = (u8)t;

        if (t != 0) { ce_part -= __logf(pt); cnt_part++; }
    }

    #pragma unroll
    for (int off = 32; off > 0; off >>= 1) {
        ce_part  += __shfl_down(ce_part, off);
        cnt_part += __shfl_down(cnt_part, off);
    }
    if ((threadIdx.x & 63) == 0) {
        atomicAdd(ce_sum, ce_part);
        atomicAdd(valid_cnt, cnt_part);
    }
}

// ---------------- k1b: histogram from packed bins ----------------
__global__ void k1b_hist(
    const u32* __restrict__ bins, const u8* __restrict__ t8, int P,
    u32* __restrict__ dumps)
{
    __shared__ u32 h[NCTR];              // 20 KiB
    for (int i = threadIdx.x; i < NCTR; i += BLK) h[i] = 0;
    __syncthreads();

    int tid = blockIdx.x * BLK + threadIdx.x;
    for (int idx = tid; idx < P; idx += NBLK * BLK) {
        u32 w0 = bins[idx];
        u32 w1 = bins[P + idx];
        u32 w2 = bins[2 * P + idx];
        u32 w3 = bins[3 * P + idx];
        u32 w4 = bins[4 * P + idx];
        int t = t8[idx];
        u32 w[5] = { w0, w1, w2, w3, w4 };
        #pragma unroll
        for (int j = 0; j < 5; ++j) {
            #pragma unroll
            for (int k = 0; k < 4; ++k) {
                int c = j * 4 + k;
                u32 b = (w[j] >> (8 * k)) & 255u;
                atomicAdd(&h[(u32)c * 256u + b], (c == t) ? 0x10001u : 1u);
            }
        }
    }

    __syncthreads();
    u32* d = dumps + (size_t)blockIdx.x * NCTR;
    for (int i = threadIdx.x; i < NCTR; i += BLK) d[i] = h[i];
}

// ---------------- k2a: reduce + unpack per-block dumps ----------------
__global__ __launch_bounds__(256) void k2a_reduce(
    const u32* __restrict__ dumps, u32* __restrict__ final_hist, int nblk, int chunk)
{
    int counter = (blockIdx.x % 20) * 256 + threadIdx.x;   // 20*256 == 5120
    int part    = blockIdx.x / 20;
    int b0 = part * chunk;
    int b1 = b0 + chunk; if (b1 > nblk) b1 = nblk;
    u32 lo = 0, hi = 0;
    for (int blk = b0; blk < b1; ++blk) {
        u32 v = dumps[(size_t)blk * NCTR + counter];
        lo += v & 0xFFFFu;
        hi += v >> 16;
    }
    if (lo) atomicAdd(&final_hist[counter], lo);           // tot
    if (hi) atomicAdd(&final_hist[NCTR + counter], hi);    // fg
}

// ---------------- k2b: per-class descending bin scan + finalize ----------------
__device__ __forceinline__ float jac_of(float gts, u32 cf, u32 ct)
{
    float I = gts - (float)cf;
    float U = gts + (float)ct - (float)cf;
    return 1.0f - I / U;
}

__global__ __launch_bounds__(256) void k2b_final(
    const u32* __restrict__ final_hist, const float* __restrict__ ce_sum,
    const u32* __restrict__ valid_cnt, float* __restrict__ outp)
{
    __shared__ u64 sc[NB];
    __shared__ float red[NB];
    int t = threadIdx.x;

    float lovsum = 0.f;
    int prescnt = 0;

    for (int c = 0; c < NC; ++c) {
        int b = NB - 1 - t;                 // descending error order
        u32 tot = final_hist[c * NB + b];
        u32 fg  = final_hist[NCTR + c * NB + b];
        u64 v = ((u64)fg << 32) | (u64)tot;

        sc[t] = v;
        __syncthreads();
        for (int off = 1; off < NB; off <<= 1) {
            u64 add = (t >= off) ? sc[t - off] : 0ull;
            __syncthreads();
            sc[t] += add;
            __syncthreads();
        }
        u64 incl  = sc[t];
        u64 total = sc[NB - 1];
        float gts = (float)(u32)(total >> 32);

        float contrib = 0.f;
        if (gts > 0.f) {
            u64 excl = incl - v;
            float jE = jac_of(gts, (u32)(excl >> 32), (u32)excl);
            float jI = jac_of(gts, (u32)(incl >> 32), (u32)incl);
            float eb = ((float)b + 0.5f) * (1.0f / (float)NB);
            contrib = eb * (jI - jE);
        }

        red[t] = contrib;
        __syncthreads();
        #pragma unroll
        for (int off = NB / 2; off > 0; off >>= 1) {
            if (t < off) red[t] += red[t + off];
            __syncthreads();
        }
        if (t == 0 && gts > 0.f) { lovsum += red[0]; prescnt++; }
        __syncthreads();
    }

    if (t == 0) {
        u32 vc = *valid_cnt; if (vc < 1u) vc = 1u;
        float ce = *ce_sum / (float)vc;
        int pc = prescnt < 1 ? 1 : prescnt;
        float lov = lovsum / (float)pc;
        outp[0] = 2.0f * ce;
        outp[1] = 6.0f * lov;
    }
}

// ---------------- launch ----------------
extern "C" void kernel_launch(void* const* d_in, const int* in_sizes, int n_in,
                              void* d_out, int out_size, void* d_ws, size_t ws_size,
                              hipStream_t stream)
{
    const float* logits = (const float*)d_in[0];
    const int*   tgt    = (const int*)d_in[1];
    int P = in_sizes[1];

    char* ws = (char*)d_ws;
    u32*  final_hist = (u32*)ws;
    float* ce_sum    = (float*)(ws + OFF_CE);
    u32*  valid_cnt  = (u32*)(ws + OFF_CNT);
    u32*  dumps      = (u32*)(ws + OFF_DUMPS);

    size_t off_bins = (size_t)OFF_DUMPS + (size_t)NBLK * DUMP_BYTES;
    u32* bins = (u32*)(ws + off_bins);
    u8*  t8   = (u8*)(ws + off_bins + (size_t)5 * P * 4);

    hipMemsetAsync(d_ws, 0, RESERVED, stream);
    hipLaunchKernelGGL(k1a_bins, dim3(NBLK), dim3(BLK), 0, stream,
                       logits, tgt, P, bins, t8, ce_sum, valid_cnt);
    hipLaunchKernelGGL(k1b_hist, dim3(NBLK), dim3(BLK), 0, stream,
                       bins, t8, P, dumps);
    int split = 32;
    int chunk = (NBLK + split - 1) / split;
    hipLaunchKernelGGL(k2a_reduce, dim3(20 * split), dim3(256), 0, stream,
                       dumps, final_hist, NBLK, chunk);
    hipLaunchKernelGGL(k2b_final, dim3(1), dim3(NB), 0, stream,
                       final_hist, ce_sum, valid_cnt, (float*)d_out);
}